// Round 2
// baseline (376.397 us; speedup 1.0000x reference)
//
#include <hip/hip_runtime.h>

#define B_WIN 1024
#define NTOK 64
#define CDIM 256
#define NH 8
#define HD 32

typedef __attribute__((ext_vector_type(8))) short short8;
typedef __attribute__((ext_vector_type(4))) float f32x4;

__device__ __forceinline__ unsigned short f2bf(float f) {
    unsigned int u = __float_as_uint(f);
    u += 0x7fff + ((u >> 16) & 1);   // round-to-nearest-even
    return (unsigned short)(u >> 16);
}

// ---------------- prep: transpose + convert weights to bf16 ----------------
__global__ void prep_weights(const float* __restrict__ w_qkv,
                             const float* __restrict__ w_proj,
                             unsigned short* __restrict__ wqkvT,
                             unsigned short* __restrict__ wprojT) {
    int tid = blockIdx.x * blockDim.x + threadIdx.x;
    int stride = gridDim.x * blockDim.x;
    // wqkvT[c][k] = w_qkv[k][c], c<768, k<256
    for (int i = tid; i < 768 * 256; i += stride) {
        int c = i >> 8, k = i & 255;
        wqkvT[i] = f2bf(w_qkv[k * 768 + c]);
    }
    // wprojT[c][k] = w_proj[k][c], c<256, k<256
    for (int i = tid; i < 256 * 256; i += stride) {
        int c = i >> 8, k = i & 255;
        wprojT[i] = f2bf(w_proj[k * 256 + c]);
    }
}

// ---------------- kernel 1: fused QKV projection GEMM ----------------------
// per-window block: M=64 rows, N=768 cols, K=256.  4 waves, each 192 cols in
// 3 chunks of 64.  Output scattered as Q[n][d] (scaled), K[n][d], V^T[d][n].
// Workspace is indexed by (b - wbase) so sliced launches reuse a small ws.
__global__ __launch_bounds__(256) void qkv_gemm(
    const float* __restrict__ x, const float* __restrict__ b_qkv,
    const unsigned short* __restrict__ wqkvT,
    unsigned short* __restrict__ Qws, unsigned short* __restrict__ Kws,
    unsigned short* __restrict__ VTws, int wbase) {
    const int bw = blockIdx.x;            // ws-local window index
    const int b = wbase + bw;             // global window index
    const int tid = threadIdx.x;
    const int wv = tid >> 6;
    const int lane = tid & 63;
    const int lr = lane & 15;
    const int g = lane >> 4;
    const float scale = 0.17677669529663687f;  // hd^-0.5

    const float* xwin = x + (size_t)b * NTOK * CDIM;

    for (int ch = 0; ch < 3; ++ch) {
        const int c0 = wv * 192 + ch * 64;
        f32x4 acc[4][4];
        #pragma unroll
        for (int i = 0; i < 4; ++i)
            #pragma unroll
            for (int j = 0; j < 4; ++j)
                acc[i][j] = (f32x4){0.f, 0.f, 0.f, 0.f};

        for (int kt = 0; kt < 8; ++kt) {
            const int k0 = kt * 32 + g * 8;
            short8 af[4];
            #pragma unroll
            for (int mt = 0; mt < 4; ++mt) {
                const float* p = xwin + (mt * 16 + lr) * CDIM + k0;
                f32x4 lo = *(const f32x4*)p;
                f32x4 hi = *(const f32x4*)(p + 4);
                short8 v;
                v[0] = f2bf(lo[0]); v[1] = f2bf(lo[1]);
                v[2] = f2bf(lo[2]); v[3] = f2bf(lo[3]);
                v[4] = f2bf(hi[0]); v[5] = f2bf(hi[1]);
                v[6] = f2bf(hi[2]); v[7] = f2bf(hi[3]);
                af[mt] = v;
            }
            #pragma unroll
            for (int ct = 0; ct < 4; ++ct) {
                short8 bfr = *(const short8*)(wqkvT + (size_t)(c0 + ct * 16 + lr) * CDIM + k0);
                #pragma unroll
                for (int mt = 0; mt < 4; ++mt)
                    acc[mt][ct] = __builtin_amdgcn_mfma_f32_16x16x32_bf16(
                        af[mt], bfr, acc[mt][ct], 0, 0, 0);
            }
        }
        // epilogue: bias (+scale for Q), scatter to ws
        #pragma unroll
        for (int ct = 0; ct < 4; ++ct) {
            int c = c0 + ct * 16 + lr;
            int m = c >> 8;           // 0=Q 1=K 2=V (uniform per 16-lane group)
            int rem = c & 255;
            int h = rem >> 5, d = rem & 31;
            float bias = b_qkv[c];
            #pragma unroll
            for (int mt = 0; mt < 4; ++mt) {
                int n0 = mt * 16 + g * 4;
                if (m == 2) {
                    unsigned short* dst =
                        VTws + ((size_t)(bw * NH + h) * HD + d) * NTOK + n0;
                    ushort4 pk;
                    pk.x = f2bf(acc[mt][ct][0] + bias);
                    pk.y = f2bf(acc[mt][ct][1] + bias);
                    pk.z = f2bf(acc[mt][ct][2] + bias);
                    pk.w = f2bf(acc[mt][ct][3] + bias);
                    *(ushort4*)dst = pk;
                } else {
                    unsigned short* base =
                        (m == 0 ? Qws : Kws) + (size_t)(bw * NH + h) * NTOK * HD + d;
                    float mul = (m == 0) ? scale : 1.0f;
                    #pragma unroll
                    for (int r = 0; r < 4; ++r)
                        base[(n0 + r) * HD] = f2bf((acc[mt][ct][r] + bias) * mul);
                }
            }
        }
    }
}

// ---------------- kernel 2: attention + fused output projection ------------
// per-window block, 4 waves; each wave does heads {wv, wv+4} sequentially.
// S = Q K^T (+mask) -> softmax (shfl over 16-lane group) -> P (LDS, swizzled)
// O = P V  -> swizzled 64x256 attn-out LDS -> out-proj GEMM + bias.
__global__ __launch_bounds__(256) void attn_proj(
    const unsigned short* __restrict__ Qws, const unsigned short* __restrict__ Kws,
    const unsigned short* __restrict__ VTws, const float* __restrict__ mask,
    const unsigned short* __restrict__ wprojT, const float* __restrict__ b_proj,
    float* __restrict__ out, int wbase) {
    __shared__ unsigned short p_lds[4][64 * 64];   // per-wave P, XOR-swizzled
    __shared__ unsigned short ao_lds[64 * 256];    // attn-out, XOR-swizzled

    const int bw = blockIdx.x;
    const int b = wbase + bw;
    const int tid = threadIdx.x;
    const int wv = tid >> 6;
    const int lane = tid & 63;
    const int lr = lane & 15;
    const int g = lane >> 4;
    const float* mwin = mask + (size_t)(b & 63) * NTOK * NTOK;

    for (int hi2 = 0; hi2 < 2; ++hi2) {
        const int h = wv + hi2 * 4;
        const unsigned short* Qh = Qws + (size_t)(bw * NH + h) * NTOK * HD;
        const unsigned short* Kh = Kws + (size_t)(bw * NH + h) * NTOK * HD;
        const unsigned short* Vh = VTws + (size_t)(bw * NH + h) * HD * NTOK;

        // ---- S = Q K^T  (K=32 -> one MFMA per 16x16 tile) ----
        short8 qf[4], kf[4];
        #pragma unroll
        for (int t = 0; t < 4; ++t) {
            qf[t] = *(const short8*)(Qh + (t * 16 + lr) * HD + g * 8);
            kf[t] = *(const short8*)(Kh + (t * 16 + lr) * HD + g * 8);
        }
        f32x4 s[4][4];
        #pragma unroll
        for (int mt = 0; mt < 4; ++mt)
            #pragma unroll
            for (int nt = 0; nt < 4; ++nt)
                s[mt][nt] = __builtin_amdgcn_mfma_f32_16x16x32_bf16(
                    qf[mt], kf[nt], (f32x4){0.f, 0.f, 0.f, 0.f}, 0, 0, 0);

        // ---- mask add + row softmax + P -> LDS ----
        unsigned short* pl = p_lds[wv];
        #pragma unroll
        for (int mt = 0; mt < 4; ++mt) {
            #pragma unroll
            for (int r = 0; r < 4; ++r) {
                int n = mt * 16 + g * 4 + r;
                const float* mrow = mwin + n * 64 + lr;
                float v0 = s[mt][0][r] + mrow[0];
                float v1 = s[mt][1][r] + mrow[16];
                float v2 = s[mt][2][r] + mrow[32];
                float v3 = s[mt][3][r] + mrow[48];
                float mx = fmaxf(fmaxf(v0, v1), fmaxf(v2, v3));
                #pragma unroll
                for (int sh = 1; sh < 16; sh <<= 1) mx = fmaxf(mx, __shfl_xor(mx, sh));
                v0 = __expf(v0 - mx); v1 = __expf(v1 - mx);
                v2 = __expf(v2 - mx); v3 = __expf(v3 - mx);
                float sum = v0 + v1 + v2 + v3;
                #pragma unroll
                for (int sh = 1; sh < 16; sh <<= 1) sum += __shfl_xor(sum, sh);
                float inv = 1.0f / sum;
                int rb = n * 64;
                int sw = (n & 7) << 3;
                pl[(rb + lr)      ^ sw] = f2bf(v0 * inv);
                pl[(rb + lr + 16) ^ sw] = f2bf(v1 * inv);
                pl[(rb + lr + 32) ^ sw] = f2bf(v2 * inv);
                pl[(rb + lr + 48) ^ sw] = f2bf(v3 * inv);
            }
        }

        // ---- O = P V ----
        f32x4 o[4][2];
        #pragma unroll
        for (int mt = 0; mt < 4; ++mt)
            #pragma unroll
            for (int dt = 0; dt < 2; ++dt)
                o[mt][dt] = (f32x4){0.f, 0.f, 0.f, 0.f};
        #pragma unroll
        for (int kt2 = 0; kt2 < 2; ++kt2) {
            short8 pa[4], vf[2];
            #pragma unroll
            for (int mt = 0; mt < 4; ++mt) {
                int row = mt * 16 + lr;
                int idx = (row * 64 + kt2 * 32 + g * 8) ^ ((row & 7) << 3);
                pa[mt] = *(const short8*)(pl + idx);
            }
            #pragma unroll
            for (int dt = 0; dt < 2; ++dt)
                vf[dt] = *(const short8*)(Vh + (dt * 16 + lr) * NTOK + kt2 * 32 + g * 8);
            #pragma unroll
            for (int mt = 0; mt < 4; ++mt)
                #pragma unroll
                for (int dt = 0; dt < 2; ++dt)
                    o[mt][dt] = __builtin_amdgcn_mfma_f32_16x16x32_bf16(
                        pa[mt], vf[dt], o[mt][dt], 0, 0, 0);
        }
        // ---- attn-out -> LDS (swizzled), layout [n][h*32+d] ----
        #pragma unroll
        for (int mt = 0; mt < 4; ++mt)
            #pragma unroll
            for (int dt = 0; dt < 2; ++dt) {
                int c = h * 32 + dt * 16 + lr;
                #pragma unroll
                for (int r = 0; r < 4; ++r) {
                    int n = mt * 16 + g * 4 + r;
                    ao_lds[(n * 256 + c) ^ ((n & 7) << 3)] = f2bf(o[mt][dt][r]);
                }
            }
    }
    __syncthreads();

    // ---- out-proj: (64x256) @ (256x256) + bias ----
    f32x4 acc2[4][4];
    #pragma unroll
    for (int i = 0; i < 4; ++i)
        #pragma unroll
        for (int j = 0; j < 4; ++j)
            acc2[i][j] = (f32x4){0.f, 0.f, 0.f, 0.f};
    const int c0 = wv * 64;
    for (int kt = 0; kt < 8; ++kt) {
        short8 af2[4];
        #pragma unroll
        for (int mt = 0; mt < 4; ++mt) {
            int row = mt * 16 + lr;
            int idx = (row * 256 + kt * 32 + g * 8) ^ ((row & 7) << 3);
            af2[mt] = *(const short8*)(ao_lds + idx);
        }
        #pragma unroll
        for (int ct = 0; ct < 4; ++ct) {
            short8 bf2 = *(const short8*)(wprojT + (size_t)(c0 + ct * 16 + lr) * 256 + kt * 32 + g * 8);
            #pragma unroll
            for (int mt = 0; mt < 4; ++mt)
                acc2[mt][ct] = __builtin_amdgcn_mfma_f32_16x16x32_bf16(
                    af2[mt], bf2, acc2[mt][ct], 0, 0, 0);
        }
    }
    float* ob = out + (size_t)b * NTOK * CDIM;
    #pragma unroll
    for (int ct = 0; ct < 4; ++ct) {
        int c = c0 + ct * 16 + lr;
        float bias = b_proj[c];
        #pragma unroll
        for (int mt = 0; mt < 4; ++mt)
            #pragma unroll
            for (int r = 0; r < 4; ++r) {
                int n = mt * 16 + g * 4 + r;
                ob[n * 256 + c] = acc2[mt][ct][r] + bias;
            }
    }
}

extern "C" void kernel_launch(void* const* d_in, const int* in_sizes, int n_in,
                              void* d_out, int out_size, void* d_ws, size_t ws_size,
                              hipStream_t stream) {
    const float* x      = (const float*)d_in[0];
    const float* mask   = (const float*)d_in[1];
    const float* w_qkv  = (const float*)d_in[2];
    const float* b_qkv  = (const float*)d_in[3];
    const float* w_proj = (const float*)d_in[4];
    const float* b_proj = (const float*)d_in[5];
    float* out = (float*)d_out;

    // ws layout: [wqkvT 768*256][wprojT 256*256][Q | K | VT for W windows]
    const size_t wT_elems = 768 * 256 + 256 * 256;         // 262144
    const size_t per_win  = (size_t)NH * NTOK * HD * 3;    // 49152 elems/window

    // pick largest power-of-2 window-slice W (<=1024) whose staging fits ws
    size_t avail = ws_size / 2;                            // in bf16 elems
    int W = 1024;
    while (W > 1 && wT_elems + (size_t)W * per_win > avail) W >>= 1;

    unsigned short* wqkvT  = (unsigned short*)d_ws;
    unsigned short* wprojT = wqkvT + 768 * 256;
    unsigned short* Qws    = wprojT + 256 * 256;
    unsigned short* Kws    = Qws + (size_t)W * NH * NTOK * HD;
    unsigned short* VTws   = Kws + (size_t)W * NH * NTOK * HD;

    prep_weights<<<256, 256, 0, stream>>>(w_qkv, w_proj, wqkvT, wprojT);
    for (int wbase = 0; wbase < B_WIN; wbase += W) {
        qkv_gemm<<<W, 256, 0, stream>>>(x, b_qkv, wqkvT, Qws, Kws, VTws, wbase);
        attn_proj<<<W, 256, 0, stream>>>(Qws, Kws, VTws, mask, wprojT, b_proj,
                                         out, wbase);
    }
}